// Round 11
// baseline (20.195 us; speedup 1.0000x reference)
//
#include <hip/hip_runtime.h>
#include <stdint.h>

typedef _Float16 half_t;
typedef _Float16 v4h __attribute__((ext_vector_type(4)));
typedef _Float16 v8h __attribute__((ext_vector_type(8)));
typedef float v4f __attribute__((ext_vector_type(4)));

#define HH 256
#define WW 256
#define HW (HH*WW)
#define TH 32
#define TW 16
#define NROWS (TH+12)     // 44 real rows
#define NRP   48          // padded to 48 so staging = exactly 3 iters/thread
#define NPX   (TW+16)     // 32
#define PXS   40          // f16 per px: 32 ch (unit-reordered) + 8 pad; 80B stride
#define NTHREADS 1024
#define L2E 1.44269504088896340736f

__global__ __launch_bounds__(NTHREADS, 4)
void corr_recon(const float* __restrict__ ft, const float* __restrict__ fr,
                const float* __restrict__ img, float* __restrict__ out)
{
    __shared__ half_t frl[NRP * NPX * PXS];     // 122880 B
    __shared__ float  img_lds[NRP * NPX];       // 6144 B   (total 129 KB, 1 block/CU)

    // XCD-chunked bijective swizzle: 256 blocks = 8 chunks of 32
    const int bid0 = blockIdx.x;
    const int bid  = (bid0 & 7) * 32 + (bid0 >> 3);

    const int b0  = bid >> 7;
    const int rb  = bid & 127;
    const int y0  = (rb >> 4) * TH;    // 8 row-bands of 32
    const int x0t = (rb & 15) * TW;    // 16 col-bands of 16

    const int tid  = threadIdx.x;
    const int lane = tid & 63;
    const int w    = tid >> 6;         // wave 0..15 -> query rows y0+2w, y0+2w+1
    const int n    = lane & 15;        // MFMA col lane (key px slot)
    const int g    = lane >> 4;        // MFMA k-group

    const float* frb = fr  + (size_t)b0 * 32 * HW;
    const float* ftb = ft  + (size_t)b0 * 32 * HW;
    const float* imb = img + (size_t)b0 * HW;

    // ---- A-fragment f32 loads ISSUED FIRST (latency hides under staging) ----
    const int y = y0 + 2*w;
    float at[16];
    {
        const float* fa = ftb + (size_t)y * WW + (x0t + n);
        #pragma unroll
        for (int j = 0; j < 4; ++j) {
            at[j]    = fa[(size_t)(4*g + j)      * HW];
            at[4+j]  = fa[(size_t)(16 + 4*g + j) * HW];
            at[8+j]  = fa[WW + (size_t)(4*g + j)      * HW];
            at[12+j] = fa[WW + (size_t)(16 + 4*g + j) * HW];
        }
    }

    // ---- stage fr: branchless edge handling, exactly 3 iters/thread.
    //      granule q (ch 4q..4q+3) -> f16 offset 8*(q&3)+4*(q>>2) so the 16B
    //      unit at offset 16g = the mfma_f32_16x16x32_f16 k-slice for group g.
    #pragma unroll
    for (int k = 0; k < 3; ++k) {
        const int i   = tid + k * NTHREADS;     // < 3072 = 48*8*8
        const int px4 = i & 7;
        const int q   = (i >> 3) & 7;
        const int row = i >> 6;                 // 0..47 (44..47 = pad rows)
        const int gy  = y0 - 6 + row;
        const int gx  = x0t - 6 + px4 * 4;
        const int gyc = min(max(gy, 0), HH-1);
        const int gxs = min(max(gx, 0), WW-4);
        const int del = gx - gxs;               // 0 interior; ±2 at partial edges
        const bool oky = (gy == gyc);
        const float* src = frb + ((size_t)(4*q) * HH + gyc) * WW + gxs;
        float4 v0 = *(const float4*)(src);
        float4 v1 = *(const float4*)(src + HW);
        float4 v2 = *(const float4*)(src + 2*HW);
        float4 v3 = *(const float4*)(src + 3*HW);
        float l0[4] = {v0.x,v0.y,v0.z,v0.w};
        float l1[4] = {v1.x,v1.y,v1.z,v1.w};
        float l2[4] = {v2.x,v2.y,v2.z,v2.w};
        float l3[4] = {v3.x,v3.y,v3.z,v3.w};
        bool ok[4];
        #pragma unroll
        for (int e = 0; e < 4; ++e) {
            const int x = gx + e;
            ok[e] = oky && (x >= 0) && (x < WW);
        }
        const int qo = 8*(q & 3) + 4*(q >> 2);
        #pragma unroll
        for (int e = 0; e < 4; ++e) {
            // source index within the loaded quad: e+del, clamped (masked when invalid)
            const int s  = min(max(e + del, 0), 3);
            const float f0 = ok[e] ? l0[s] : 0.f;
            const float f1 = ok[e] ? l1[s] : 0.f;
            const float f2 = ok[e] ? l2[s] : 0.f;
            const float f3 = ok[e] ? l3[s] : 0.f;
            v4h pk;
            pk[0] = (half_t)f0; pk[1] = (half_t)f1;
            pk[2] = (half_t)f2; pk[3] = (half_t)f3;
            *(v4h*)&frl[((row * NPX) + px4*4 + e) * PXS + qo] = pk;
        }
    }
    // ---- stage img tile (one masked iteration; guarded edge fallback) ----
    if (tid < NRP * 8) {
        const int px4 = tid & 7;
        const int row = tid >> 3;
        const int gy = y0 - 6 + row;
        const int gx = x0t - 6 + px4*4;
        const int gyc = min(max(gy, 0), HH-1);
        const bool oky = (gy == gyc);
        const float* p = imb + (size_t)gyc * WW;
        float v[4];
        if (oky && gx >= 0 && gx + 3 < WW) {
            float4 t4 = *(const float4*)(p + gx);
            v[0]=t4.x; v[1]=t4.y; v[2]=t4.z; v[3]=t4.w;
        } else {
            #pragma unroll
            for (int e = 0; e < 4; ++e) {
                int x = gx + e;
                v[e] = (oky && x >= 0 && x < WW) ? p[x] : 0.f;
            }
        }
        float4 f4; f4.x=v[0]; f4.y=v[1]; f4.z=v[2]; f4.w=v[3];
        *(float4*)&img_lds[row*NPX + px4*4] = f4;
    }

    // ---- convert A temps -> fragments (pre-scaled by log2e) ----
    v8h a0, a1;
    #pragma unroll
    for (int j = 0; j < 4; ++j) {
        a0[j]   = (half_t)(at[j]    * L2E);
        a0[4+j] = (half_t)(at[4+j]  * L2E);
        a1[j]   = (half_t)(at[8+j]  * L2E);
        a1[4+j] = (half_t)(at[12+j] * L2E);
    }

    // ---- per-lane displacement-band biases (log2 domain; exp2(-1e4)==0) ----
    v4f bias0, bias1;
    #pragma unroll
    for (int r = 0; r < 4; ++r) {
        const int m  = 4*g + r;
        const int d0 = n - m;            // key-tile 0
        const int d1 = 16 + n - m;       // key-tile +16
        bias0[r] = (d0 >= 0 && d0 <= 12) ? 0.f : -1e4f;
        bias1[r] = (d1 >= 0 && d1 <= 12) ? 0.f : -1e4f;
    }
    const int dm = n - 4*g;              // select: cond_r = (dm >= r)

    __syncthreads();

    v4f lp0 = {0,0,0,0}, ap0 = {0,0,0,0};
    v4f lp1 = {0,0,0,0}, ap1 = {0,0,0,0};

    auto STEP = [&](const v8h& a, v4f& lp, v4f& ap,
                    const v8h& B0, const v8h& B1, float iw0, float iw1) {
        v4f c0 = __builtin_amdgcn_mfma_f32_16x16x32_f16(a, B0, bias0, 0, 0, 0);
        v4f c1 = __builtin_amdgcn_mfma_f32_16x16x32_f16(a, B1, bias1, 0, 0, 0);
        #pragma unroll
        for (int r = 0; r < 4; ++r) {
            const bool cond = (dm >= r);
            float cs  = cond ? c0[r] : c1[r];
            float iws = cond ? iw0   : iw1;
            float e = __builtin_amdgcn_exp2f(cs);
            lp[r] += e;
            ap[r] += e * iws;
        }
    };

    // ---- main loop: rows 2w..2w+13; row serves job0 at dy=rr, job1 at dy=rr-1.
    //      1-deep prefetch (C/N rotation). ----
    const half_t* prd = &frl[(2*w * NPX + n) * PXS + 8*g];
    const float*  ird = &img_lds[2*w * NPX + n];

    v8h C0 = *(const v8h*)(prd);
    v8h C1 = *(const v8h*)(prd + 16*PXS);
    float ci0 = ird[0], ci1 = ird[16];

    prd += NPX*PXS; ird += NPX;
    v8h N0 = *(const v8h*)(prd);
    v8h N1 = *(const v8h*)(prd + 16*PXS);
    float ni0 = ird[0], ni1 = ird[16];

    STEP(a0, lp0, ap0, C0, C1, ci0, ci1);          // rr = 0: job0 only

    #pragma unroll 1
    for (int rr = 1; rr < 13; ++rr) {
        C0 = N0; C1 = N1; ci0 = ni0; ci1 = ni1;
        prd += NPX*PXS; ird += NPX;
        N0 = *(const v8h*)(prd);
        N1 = *(const v8h*)(prd + 16*PXS);
        ni0 = ird[0]; ni1 = ird[16];
        STEP(a0, lp0, ap0, C0, C1, ci0, ci1);      // job0, dy = rr
        STEP(a1, lp1, ap1, C0, C1, ci0, ci1);      // job1, dy = rr-1
    }
    STEP(a1, lp1, ap1, N0, N1, ni0, ni1);          // rr = 13: job1 only

    // ---- reduce over the 16 key-px lanes; write 2 rows × 16 px per wave ----
    #pragma unroll
    for (int r = 0; r < 4; ++r) {
        float l0 = lp0[r], v0 = ap0[r], l1 = lp1[r], v1 = ap1[r];
        l0 += __shfl_xor(l0, 1);  v0 += __shfl_xor(v0, 1);
        l1 += __shfl_xor(l1, 1);  v1 += __shfl_xor(v1, 1);
        l0 += __shfl_xor(l0, 2);  v0 += __shfl_xor(v0, 2);
        l1 += __shfl_xor(l1, 2);  v1 += __shfl_xor(v1, 2);
        l0 += __shfl_xor(l0, 4);  v0 += __shfl_xor(v0, 4);
        l1 += __shfl_xor(l1, 4);  v1 += __shfl_xor(v1, 4);
        l0 += __shfl_xor(l0, 8);  v0 += __shfl_xor(v0, 8);
        l1 += __shfl_xor(l1, 8);  v1 += __shfl_xor(v1, 8);
        lp0[r] = l0; ap0[r] = v0; lp1[r] = l1; ap1[r] = v1;
    }
    if (n < 4) {
        const float l0 = n==0 ? lp0[0] : n==1 ? lp0[1] : n==2 ? lp0[2] : lp0[3];
        const float v0 = n==0 ? ap0[0] : n==1 ? ap0[1] : n==2 ? ap0[2] : ap0[3];
        const float l1 = n==0 ? lp1[0] : n==1 ? lp1[1] : n==2 ? lp1[2] : lp1[3];
        const float v1 = n==0 ? ap1[0] : n==1 ? ap1[1] : n==2 ? ap1[2] : ap1[3];
        float* orow = out + (size_t)b0 * HW + (size_t)y * WW + x0t + 4*g + n;
        orow[0]  = v0 / l0;
        orow[WW] = v1 / l1;
    }
}

extern "C" void kernel_launch(void* const* d_in, const int* in_sizes, int n_in,
                              void* d_out, int out_size, void* d_ws, size_t ws_size,
                              hipStream_t stream)
{
    const float* ft  = (const float*)d_in[0];  // feats_t  (2,32,256,256) f32
    const float* fr  = (const float*)d_in[1];  // feats_r  (2,32,256,256) f32
    const float* img = (const float*)d_in[2];  // img_r    (2,1,256,256)  f32
    float* out = (float*)d_out;                // (2,1,256,256) f32
    (void)in_sizes; (void)n_in; (void)out_size; (void)d_ws; (void)ws_size;
    corr_recon<<<256, NTHREADS, 0, stream>>>(ft, fr, img, out);
}

// Round 12
// 19.535 us; speedup vs baseline: 1.0338x; 1.0338x over previous
//
#include <hip/hip_runtime.h>
#include <stdint.h>

typedef _Float16 half_t;
typedef _Float16 v4h __attribute__((ext_vector_type(4)));
typedef _Float16 v8h __attribute__((ext_vector_type(8)));
typedef float v4f __attribute__((ext_vector_type(4)));

#define HH 256
#define WW 256
#define HW (HH*WW)
#define TH 32
#define TW 16
#define NROWS (TH+12)     // 44
#define NPX   (TW+16)     // 32
#define PXS   40          // f16 per px: 32 ch (unit-reordered) + 8 pad; 80B stride
#define NTHREADS 1024
#define RSPLIT 30         // rows [0,30) staged by all; [30,44) by waves 8..15
#define L2E 1.44269504088896340736f

__global__ __launch_bounds__(NTHREADS, 4)
void corr_recon(const float* __restrict__ ft, const float* __restrict__ fr,
                const float* __restrict__ img, float* __restrict__ out)
{
    __shared__ half_t frl[NROWS * NPX * PXS];   // 112640 B
    __shared__ float  img_lds[NROWS * NPX];     // 5632 B

    // XCD-chunked bijective swizzle: 256 blocks = 8 chunks of 32
    const int bid0 = blockIdx.x;
    const int bid  = (bid0 & 7) * 32 + (bid0 >> 3);

    const int b0  = bid >> 7;
    const int rb  = bid & 127;
    const int y0  = (rb >> 4) * TH;    // 8 row-bands of 32
    const int x0t = (rb & 15) * TW;    // 16 col-bands of 16

    const int tid  = threadIdx.x;
    const int lane = tid & 63;
    const int w    = tid >> 6;         // wave 0..15 -> query rows y0+2w, y0+2w+1
    const int n    = lane & 15;        // MFMA col lane (key px slot)
    const int g    = lane >> 4;        // MFMA k-group

    const float* frb = fr  + (size_t)b0 * 32 * HW;
    const float* ftb = ft  + (size_t)b0 * 32 * HW;
    const float* imb = img + (size_t)b0 * HW;

    // ---- staging lambdas (bodies identical to R10, parameterized by row range) ----
    // granule q (ch 4q..4q+3) -> f16 offset 8*(q&3)+4*(q>>2): the 16B unit at
    // offset 16g holds ch {4g..4g+3, 16+4g..16+4g+3} = the x32 k-slice for group g.
    auto stage_fr = [&](int r0, int nrows, int tloc, int nt) {
        const int units = nrows * 64;           // 8 granules x 8 px-quads per row
        for (int i = tloc; i < units; i += nt) {
            const int px4 = i & 7;
            const int q   = (i >> 3) & 7;
            const int row = r0 + (i >> 6);
            const int gy  = y0 - 6 + row;
            const int gx  = x0t - 6 + px4 * 4;
            const int gyc = min(max(gy, 0), HH-1);
            const bool oky = (gy == gyc);
            const float* src = frb + ((size_t)(4*q) * HH + gyc) * WW;
            float t[4][4];
            if (oky && gx >= 0 && gx + 3 < WW) {
                #pragma unroll
                for (int jc = 0; jc < 4; ++jc) {
                    float4 v = *(const float4*)(src + (size_t)jc * HW + gx);
                    t[jc][0]=v.x; t[jc][1]=v.y; t[jc][2]=v.z; t[jc][3]=v.w;
                }
            } else {
                #pragma unroll
                for (int jc = 0; jc < 4; ++jc)
                    #pragma unroll
                    for (int e = 0; e < 4; ++e) {
                        int x = gx + e;
                        t[jc][e] = (oky && x >= 0 && x < WW) ? src[(size_t)jc * HW + x] : 0.f;
                    }
            }
            const int qo = 8*(q & 3) + 4*(q >> 2);
            #pragma unroll
            for (int jp = 0; jp < 4; ++jp) {
                const int px = px4 * 4 + jp;
                v4h pk;
                pk[0] = (half_t)t[0][jp]; pk[1] = (half_t)t[1][jp];
                pk[2] = (half_t)t[2][jp]; pk[3] = (half_t)t[3][jp];
                *(v4h*)&frl[(row * NPX + px) * PXS + qo] = pk;
            }
        }
    };
    auto stage_img = [&](int r0, int nrows, int tloc, int nt) {
        const int units = nrows * 8;
        for (int i = tloc; i < units; i += nt) {
            const int px4 = i & 7;
            const int row = r0 + (i >> 3);
            const int gy = y0 - 6 + row;
            const int gx = x0t - 6 + px4*4;
            const int gyc = min(max(gy, 0), HH-1);
            const bool oky = (gy == gyc);
            const float* p = imb + (size_t)gyc * WW;
            float v[4];
            if (oky && gx >= 0 && gx + 3 < WW) {
                float4 t4 = *(const float4*)(p + gx);
                v[0]=t4.x; v[1]=t4.y; v[2]=t4.z; v[3]=t4.w;
            } else {
                #pragma unroll
                for (int e = 0; e < 4; ++e) {
                    int x = gx + e;
                    v[e] = (oky && x >= 0 && x < WW) ? p[x] : 0.f;
                }
            }
            float4 f4; f4.x=v[0]; f4.y=v[1]; f4.z=v[2]; f4.w=v[3];
            *(float4*)&img_lds[row*NPX + px4*4] = f4;
        }
    };

    // ---- phase A: all threads stage rows [0, 30) ----
    stage_fr(0, RSPLIT, tid, NTHREADS);
    stage_img(0, RSPLIT, tid, NTHREADS);

    // ---- A fragments: 2 query rows, ch {4g+j, 16+4g+j} pre-scaled by log2e ----
    const int y = y0 + 2*w;
    v8h a0, a1;
    {
        const float* fa = ftb + (size_t)y * WW + (x0t + n);
        #pragma unroll
        for (int j = 0; j < 4; ++j) {
            a0[j]   = (half_t)(fa[(size_t)(4*g + j)      * HW] * L2E);
            a0[4+j] = (half_t)(fa[(size_t)(16 + 4*g + j) * HW] * L2E);
            a1[j]   = (half_t)(fa[WW + (size_t)(4*g + j)      * HW] * L2E);
            a1[4+j] = (half_t)(fa[WW + (size_t)(16 + 4*g + j) * HW] * L2E);
        }
    }

    // ---- per-lane displacement-band biases (log2 domain; exp2(-1e4)==0) ----
    v4f bias0, bias1;
    #pragma unroll
    for (int r = 0; r < 4; ++r) {
        const int m  = 4*g + r;
        const int d0 = n - m;            // key-tile 0
        const int d1 = 16 + n - m;       // key-tile +16
        bias0[r] = (d0 >= 0 && d0 <= 12) ? 0.f : -1e4f;
        bias1[r] = (d1 >= 0 && d1 <= 12) ? 0.f : -1e4f;
    }
    const int dm = n - 4*g;              // select: cond_r = (dm >= r)

    // ---- compute lambda (identical to R10 main loop + reduce + store) ----
    auto compute_store = [&]() {
        v4f lp0 = {0,0,0,0}, ap0 = {0,0,0,0};
        v4f lp1 = {0,0,0,0}, ap1 = {0,0,0,0};

        auto STEP = [&](const v8h& a, v4f& lp, v4f& ap,
                        const v8h& B0, const v8h& B1, float iw0, float iw1) {
            v4f c0 = __builtin_amdgcn_mfma_f32_16x16x32_f16(a, B0, bias0, 0, 0, 0);
            v4f c1 = __builtin_amdgcn_mfma_f32_16x16x32_f16(a, B1, bias1, 0, 0, 0);
            #pragma unroll
            for (int r = 0; r < 4; ++r) {
                const bool cond = (dm >= r);
                float cs  = cond ? c0[r] : c1[r];
                float iws = cond ? iw0   : iw1;
                float e = __builtin_amdgcn_exp2f(cs);
                lp[r] += e;
                ap[r] += e * iws;
            }
        };

        const half_t* prd = &frl[(2*w * NPX + n) * PXS + 8*g];
        const float*  ird = &img_lds[2*w * NPX + n];

        v8h C0 = *(const v8h*)(prd);
        v8h C1 = *(const v8h*)(prd + 16*PXS);
        float ci0 = ird[0], ci1 = ird[16];

        prd += NPX*PXS; ird += NPX;
        v8h N0 = *(const v8h*)(prd);
        v8h N1 = *(const v8h*)(prd + 16*PXS);
        float ni0 = ird[0], ni1 = ird[16];

        STEP(a0, lp0, ap0, C0, C1, ci0, ci1);          // rr = 0: job0 only

        #pragma unroll 1
        for (int rr = 1; rr < 13; ++rr) {
            C0 = N0; C1 = N1; ci0 = ni0; ci1 = ni1;
            prd += NPX*PXS; ird += NPX;
            N0 = *(const v8h*)(prd);
            N1 = *(const v8h*)(prd + 16*PXS);
            ni0 = ird[0]; ni1 = ird[16];
            STEP(a0, lp0, ap0, C0, C1, ci0, ci1);      // job0, dy = rr
            STEP(a1, lp1, ap1, C0, C1, ci0, ci1);      // job1, dy = rr-1
        }
        STEP(a1, lp1, ap1, N0, N1, ni0, ni1);          // rr = 13: job1 only

        #pragma unroll
        for (int r = 0; r < 4; ++r) {
            float l0 = lp0[r], v0 = ap0[r], l1 = lp1[r], v1 = ap1[r];
            l0 += __shfl_xor(l0, 1);  v0 += __shfl_xor(v0, 1);
            l1 += __shfl_xor(l1, 1);  v1 += __shfl_xor(v1, 1);
            l0 += __shfl_xor(l0, 2);  v0 += __shfl_xor(v0, 2);
            l1 += __shfl_xor(l1, 2);  v1 += __shfl_xor(v1, 2);
            l0 += __shfl_xor(l0, 4);  v0 += __shfl_xor(v0, 4);
            l1 += __shfl_xor(l1, 4);  v1 += __shfl_xor(v1, 4);
            l0 += __shfl_xor(l0, 8);  v0 += __shfl_xor(v0, 8);
            l1 += __shfl_xor(l1, 8);  v1 += __shfl_xor(v1, 8);
            lp0[r] = l0; ap0[r] = v0; lp1[r] = l1; ap1[r] = v1;
        }
        if (n < 4) {
            const float l0 = n==0 ? lp0[0] : n==1 ? lp0[1] : n==2 ? lp0[2] : lp0[3];
            const float v0 = n==0 ? ap0[0] : n==1 ? ap0[1] : n==2 ? ap0[2] : ap0[3];
            const float l1 = n==0 ? lp1[0] : n==1 ? lp1[1] : n==2 ? lp1[2] : lp1[3];
            const float v1 = n==0 ? ap1[0] : n==1 ? ap1[1] : n==2 ? ap1[2] : ap1[3];
            float* orow = out + (size_t)b0 * HW + (size_t)y * WW + x0t + 4*g + n;
            orow[0]  = v0 / l0;
            orow[WW] = v1 / l1;
        }
    };

    __syncthreads();

    // ---- phase B: waves 0..7 compute (rows <= 29 ready); waves 8..15 stage rows 30..43 ----
    if (w < 8) {
        compute_store();
    } else {
        stage_fr(RSPLIT, NROWS - RSPLIT, tid - 512, 512);
        stage_img(RSPLIT, NROWS - RSPLIT, tid - 512, 512);
    }

    __syncthreads();

    // ---- phase C: waves 8..15 compute (rows 16..43 ready) ----
    if (w >= 8) {
        compute_store();
    }
}

extern "C" void kernel_launch(void* const* d_in, const int* in_sizes, int n_in,
                              void* d_out, int out_size, void* d_ws, size_t ws_size,
                              hipStream_t stream)
{
    const float* ft  = (const float*)d_in[0];  // feats_t  (2,32,256,256) f32
    const float* fr  = (const float*)d_in[1];  // feats_r  (2,32,256,256) f32
    const float* img = (const float*)d_in[2];  // img_r    (2,1,256,256)  f32
    float* out = (float*)d_out;                // (2,1,256,256) f32
    (void)in_sizes; (void)n_in; (void)out_size; (void)d_ws; (void)ws_size;
    corr_recon<<<256, NTHREADS, 0, stream>>>(ft, fr, img, out);
}

// Round 13
// 19.089 us; speedup vs baseline: 1.0579x; 1.0234x over previous
//
#include <hip/hip_runtime.h>
#include <stdint.h>

typedef _Float16 half_t;
typedef _Float16 v4h __attribute__((ext_vector_type(4)));
typedef _Float16 v8h __attribute__((ext_vector_type(8)));
typedef float v4f __attribute__((ext_vector_type(4)));

#define HH 256
#define WW 256
#define HW (HH*WW)
#define TH 32
#define TW 16
#define NROWS (TH+12)     // 44
#define NPX   (TW+16)     // 32
#define PXS   40          // f16 per px: 32 ch (unit-reordered) + 8 pad; 80B stride
#define NTHREADS 1024
#define NUNITS (NROWS*64) // 2816 staging units
#define L2E 1.44269504088896340736f

__global__ __launch_bounds__(NTHREADS, 4)
void corr_recon(const float* __restrict__ ft, const float* __restrict__ fr,
                const float* __restrict__ img, float* __restrict__ out)
{
    __shared__ half_t frl[NROWS * NPX * PXS];   // 112640 B
    __shared__ float  img_lds[NROWS * NPX];     // 5632 B

    // XCD-chunked bijective swizzle: 256 blocks = 8 chunks of 32
    const int bid0 = blockIdx.x;
    const int bid  = (bid0 & 7) * 32 + (bid0 >> 3);

    const int b0  = bid >> 7;
    const int rb  = bid & 127;
    const int y0  = (rb >> 4) * TH;    // 8 row-bands of 32
    const int x0t = (rb & 15) * TW;    // 16 col-bands of 16

    const int tid  = threadIdx.x;
    const int lane = tid & 63;
    const int w    = tid >> 6;         // wave 0..15 -> query rows y0+2w, y0+2w+1
    const int n    = lane & 15;        // MFMA col lane (key px slot)
    const int g    = lane >> 4;        // MFMA k-group

    const float* frb = fr  + (size_t)b0 * 32 * HW;
    const float* ftb = ft  + (size_t)b0 * 32 * HW;
    const float* imb = img + (size_t)b0 * HW;

    // ---- staging unit load/write (guarded form proven R4..R10), pipelined:
    //      issue unit k+1's global loads before unit k's cvt+ds_write so HBM
    //      round trips overlap instead of serializing through one temp set.
    auto ld_unit = [&](int i, float4* t4) {
        const int px4 = i & 7;
        const int q   = (i >> 3) & 7;
        const int row = i >> 6;
        const int gy  = y0 - 6 + row;
        const int gx  = x0t - 6 + px4 * 4;
        const int gyc = min(max(gy, 0), HH-1);
        const bool oky = (gy == gyc);
        const float* src = frb + ((size_t)(4*q) * HH + gyc) * WW;
        if (oky && gx >= 0 && gx + 3 < WW) {
            #pragma unroll
            for (int jc = 0; jc < 4; ++jc)
                t4[jc] = *(const float4*)(src + (size_t)jc * HW + gx);
        } else {
            #pragma unroll
            for (int jc = 0; jc < 4; ++jc) {
                float e0 = 0.f, e1 = 0.f, e2 = 0.f, e3 = 0.f;
                const float* s = src + (size_t)jc * HW;
                if (oky) {
                    int x0 = gx, x1 = gx+1, x2 = gx+2, x3 = gx+3;
                    e0 = (x0 >= 0 && x0 < WW) ? s[x0] : 0.f;
                    e1 = (x1 >= 0 && x1 < WW) ? s[x1] : 0.f;
                    e2 = (x2 >= 0 && x2 < WW) ? s[x2] : 0.f;
                    e3 = (x3 >= 0 && x3 < WW) ? s[x3] : 0.f;
                }
                t4[jc].x = e0; t4[jc].y = e1; t4[jc].z = e2; t4[jc].w = e3;
            }
        }
    };
    auto wr_unit = [&](int i, const float4* t4) {
        const int px4 = i & 7;
        const int q   = (i >> 3) & 7;
        const int row = i >> 6;
        const int qo  = 8*(q & 3) + 4*(q >> 2);
        const float t0[4] = {t4[0].x, t4[0].y, t4[0].z, t4[0].w};
        const float t1[4] = {t4[1].x, t4[1].y, t4[1].z, t4[1].w};
        const float t2[4] = {t4[2].x, t4[2].y, t4[2].z, t4[2].w};
        const float t3[4] = {t4[3].x, t4[3].y, t4[3].z, t4[3].w};
        #pragma unroll
        for (int jp = 0; jp < 4; ++jp) {
            const int px = px4 * 4 + jp;
            v4h pk;
            pk[0] = (half_t)t0[jp]; pk[1] = (half_t)t1[jp];
            pk[2] = (half_t)t2[jp]; pk[3] = (half_t)t3[jp];
            *(v4h*)&frl[(row * NPX + px) * PXS + qo] = pk;
        }
    };

    {
        float4 tA[4], tB[4];
        ld_unit(tid, tA);                              // unit 0 loads in flight
        ld_unit(tid + NTHREADS, tB);                   // unit 1 loads in flight
        wr_unit(tid, tA);                              // cvt+write unit 0
        if (tid < NUNITS - 2*NTHREADS)                 // 768 threads have a 3rd unit
            ld_unit(tid + 2*NTHREADS, tA);
        wr_unit(tid + NTHREADS, tB);
        if (tid < NUNITS - 2*NTHREADS)
            wr_unit(tid + 2*NTHREADS, tA);
    }

    // ---- stage img tile (352 units < 1024 threads: single shot) ----
    if (tid < NROWS * 8) {
        const int px4 = tid & 7;
        const int row = tid >> 3;
        const int gy = y0 - 6 + row;
        const int gx = x0t - 6 + px4*4;
        const int gyc = min(max(gy, 0), HH-1);
        const bool oky = (gy == gyc);
        const float* p = imb + (size_t)gyc * WW;
        float v[4];
        if (oky && gx >= 0 && gx + 3 < WW) {
            float4 t4 = *(const float4*)(p + gx);
            v[0]=t4.x; v[1]=t4.y; v[2]=t4.z; v[3]=t4.w;
        } else {
            #pragma unroll
            for (int e = 0; e < 4; ++e) {
                int x = gx + e;
                v[e] = (oky && x >= 0 && x < WW) ? p[x] : 0.f;
            }
        }
        float4 f4; f4.x=v[0]; f4.y=v[1]; f4.z=v[2]; f4.w=v[3];
        *(float4*)&img_lds[row*NPX + px4*4] = f4;
    }

    // ---- A fragments: 2 query rows, ch {4g+j, 16+4g+j} pre-scaled by log2e ----
    const int y = y0 + 2*w;
    v8h a0, a1;
    {
        const float* fa = ftb + (size_t)y * WW + (x0t + n);
        #pragma unroll
        for (int j = 0; j < 4; ++j) {
            a0[j]   = (half_t)(fa[(size_t)(4*g + j)      * HW] * L2E);
            a0[4+j] = (half_t)(fa[(size_t)(16 + 4*g + j) * HW] * L2E);
            a1[j]   = (half_t)(fa[WW + (size_t)(4*g + j)      * HW] * L2E);
            a1[4+j] = (half_t)(fa[WW + (size_t)(16 + 4*g + j) * HW] * L2E);
        }
    }

    // ---- per-lane displacement-band biases (log2 domain; exp2(-1e4)==0) ----
    v4f bias0, bias1;
    #pragma unroll
    for (int r = 0; r < 4; ++r) {
        const int m  = 4*g + r;
        const int d0 = n - m;            // key-tile 0
        const int d1 = 16 + n - m;       // key-tile +16
        bias0[r] = (d0 >= 0 && d0 <= 12) ? 0.f : -1e4f;
        bias1[r] = (d1 >= 0 && d1 <= 12) ? 0.f : -1e4f;
    }
    const int dm = n - 4*g;              // select: cond_r = (dm >= r)

    __syncthreads();

    v4f lp0 = {0,0,0,0}, ap0 = {0,0,0,0};
    v4f lp1 = {0,0,0,0}, ap1 = {0,0,0,0};

    auto STEP = [&](const v8h& a, v4f& lp, v4f& ap,
                    const v8h& B0, const v8h& B1, float iw0, float iw1) {
        v4f c0 = __builtin_amdgcn_mfma_f32_16x16x32_f16(a, B0, bias0, 0, 0, 0);
        v4f c1 = __builtin_amdgcn_mfma_f32_16x16x32_f16(a, B1, bias1, 0, 0, 0);
        #pragma unroll
        for (int r = 0; r < 4; ++r) {
            const bool cond = (dm >= r);
            float cs  = cond ? c0[r] : c1[r];
            float iws = cond ? iw0   : iw1;
            float e = __builtin_amdgcn_exp2f(cs);
            lp[r] += e;
            ap[r] += e * iws;
        }
    };

    // ---- main loop: rows 2w..2w+13; row serves job0 at dy=rr, job1 at dy=rr-1.
    //      1-deep prefetch (C/N rotation). ----
    const half_t* prd = &frl[(2*w * NPX + n) * PXS + 8*g];
    const float*  ird = &img_lds[2*w * NPX + n];

    v8h C0 = *(const v8h*)(prd);
    v8h C1 = *(const v8h*)(prd + 16*PXS);
    float ci0 = ird[0], ci1 = ird[16];

    prd += NPX*PXS; ird += NPX;
    v8h N0 = *(const v8h*)(prd);
    v8h N1 = *(const v8h*)(prd + 16*PXS);
    float ni0 = ird[0], ni1 = ird[16];

    STEP(a0, lp0, ap0, C0, C1, ci0, ci1);          // rr = 0: job0 only

    #pragma unroll 1
    for (int rr = 1; rr < 13; ++rr) {
        C0 = N0; C1 = N1; ci0 = ni0; ci1 = ni1;
        prd += NPX*PXS; ird += NPX;
        N0 = *(const v8h*)(prd);
        N1 = *(const v8h*)(prd + 16*PXS);
        ni0 = ird[0]; ni1 = ird[16];
        STEP(a0, lp0, ap0, C0, C1, ci0, ci1);      // job0, dy = rr
        STEP(a1, lp1, ap1, C0, C1, ci0, ci1);      // job1, dy = rr-1
    }
    STEP(a1, lp1, ap1, N0, N1, ni0, ni1);          // rr = 13: job1 only

    // ---- reduce over the 16 key-px lanes; write 2 rows × 16 px per wave ----
    #pragma unroll
    for (int r = 0; r < 4; ++r) {
        float l0 = lp0[r], v0 = ap0[r], l1 = lp1[r], v1 = ap1[r];
        l0 += __shfl_xor(l0, 1);  v0 += __shfl_xor(v0, 1);
        l1 += __shfl_xor(l1, 1);  v1 += __shfl_xor(v1, 1);
        l0 += __shfl_xor(l0, 2);  v0 += __shfl_xor(v0, 2);
        l1 += __shfl_xor(l1, 2);  v1 += __shfl_xor(v1, 2);
        l0 += __shfl_xor(l0, 4);  v0 += __shfl_xor(v0, 4);
        l1 += __shfl_xor(l1, 4);  v1 += __shfl_xor(v1, 4);
        l0 += __shfl_xor(l0, 8);  v0 += __shfl_xor(v0, 8);
        l1 += __shfl_xor(l1, 8);  v1 += __shfl_xor(v1, 8);
        lp0[r] = l0; ap0[r] = v0; lp1[r] = l1; ap1[r] = v1;
    }
    if (n < 4) {
        const float l0 = n==0 ? lp0[0] : n==1 ? lp0[1] : n==2 ? lp0[2] : lp0[3];
        const float v0 = n==0 ? ap0[0] : n==1 ? ap0[1] : n==2 ? ap0[2] : ap0[3];
        const float l1 = n==0 ? lp1[0] : n==1 ? lp1[1] : n==2 ? lp1[2] : lp1[3];
        const float v1 = n==0 ? ap1[0] : n==1 ? ap1[1] : n==2 ? ap1[2] : ap1[3];
        float* orow = out + (size_t)b0 * HW + (size_t)y * WW + x0t + 4*g + n;
        orow[0]  = v0 / l0;
        orow[WW] = v1 / l1;
    }
}

extern "C" void kernel_launch(void* const* d_in, const int* in_sizes, int n_in,
                              void* d_out, int out_size, void* d_ws, size_t ws_size,
                              hipStream_t stream)
{
    const float* ft  = (const float*)d_in[0];  // feats_t  (2,32,256,256) f32
    const float* fr  = (const float*)d_in[1];  // feats_r  (2,32,256,256) f32
    const float* img = (const float*)d_in[2];  // img_r    (2,1,256,256)  f32
    float* out = (float*)d_out;                // (2,1,256,256) f32
    (void)in_sizes; (void)n_in; (void)out_size; (void)d_ws; (void)ws_size;
    corr_recon<<<256, NTHREADS, 0, stream>>>(ft, fr, img, out);
}